// Round 10
// baseline (2690.030 us; speedup 1.0000x reference)
//
#include <hip/hip_runtime.h>
#include <cstdint>

#define Eexp 8
#define Bb   16384
#define Dd   512
#define Hh   512
#define Zz   64

typedef _Float16 f16x8 __attribute__((ext_vector_type(8)));
typedef float    f32x4 __attribute__((ext_vector_type(4)));

// fm16 layout: per (T=row/16, kb=k/32) a 1024-f16 block [hi 512 | lo 512];
// lane l elem j = M[T*16 + (l&15)][kb*32 + (l>>4)*8 + j]
#define OFF_ENCIN  0
#define OFF_HID0   524288
#define OFF_HID1   1048576
#define OFF_HEADS  1572864   /* mu tiles T0..3, lv tiles T4..7 */
#define OFF_DECIN  1703936
#define OFF_DHID0  1769472
#define OFF_DHID1  2293760
#define OFF_DECOUT 2818048
#define PEREXP     3342336
#define WT_TOTAL   (8 * (size_t)PEREXP)

// ---------------------------------------------------------------------------
// fp32 src -> fm16 split-f16. TR: src[K,N] (weights). !TR: src[M,K] (x).
// ---------------------------------------------------------------------------
template<bool TR>
__global__ __launch_bounds__(256)
void fmsplit(const float* __restrict__ src, _Float16* __restrict__ dst,
             int KTOT, int inner, long sStride, long dStride)
{
    __shared__ float t[64][65];
    const int e  = blockIdx.z;
    const int o0 = blockIdx.x * 64;
    const int k0 = blockIdx.y * 64;
    const float* S = src + (size_t)e * sStride;
    _Float16*    D = dst + (size_t)e * dStride;
    const int tid = threadIdx.x;
    const int rr = tid >> 4, c4 = (tid & 15) * 4;
    #pragma unroll
    for (int p = 0; p < 4; ++p) {
        const int r = rr + p * 16;
        const float4 v = *reinterpret_cast<const float4*>(
            S + (size_t)(TR ? (k0 + r) : (o0 + r)) * inner + (TR ? o0 : k0) + c4);
        t[r][c4 + 0] = v.x; t[r][c4 + 1] = v.y;
        t[r][c4 + 2] = v.z; t[r][c4 + 3] = v.w;
    }
    __syncthreads();
    const int lane = tid & 63, wid = tid >> 6;
    const int KB = KTOT >> 5;
    #pragma unroll
    for (int p = 0; p < 2; ++p) {
        const int g  = wid * 2 + p;          // 0..7 = (ot 0..3, kb 0..1)
        const int ot = g >> 1, kb = g & 1;
        const int rI = ot * 16 + (lane & 15);
        const int kI = kb * 32 + (lane >> 4) * 8;
        f16x8 hv, lv;
        #pragma unroll
        for (int j = 0; j < 8; ++j) {
            const float v = TR ? t[kI + j][rI] : t[rI][kI + j];
            const _Float16 h = (_Float16)v;
            hv[j] = h; lv[j] = (_Float16)(v - (float)h);
        }
        const size_t base = ((size_t)((o0 >> 4) + ot) * KB + (k0 >> 5) + kb) * 1024;
        *reinterpret_cast<f16x8*>(D + base + lane * 8)       = hv;
        *reinterpret_cast<f16x8*>(D + base + 512 + lane * 8) = lv;
    }
}

// z = mu + exp(0.5*lv)*eps -> fm16 split. grid B/64, K=64 (KB=2).
__global__ __launch_bounds__(256)
void zfm_kernel(const float* __restrict__ mu, const float* __restrict__ lv,
                const float* __restrict__ eps, _Float16* __restrict__ zfm)
{
    __shared__ float t[64][65];
    const int r0 = blockIdx.x * 64;
    const int tid = threadIdx.x, rr = tid >> 4, c4 = (tid & 15) * 4;
    #pragma unroll
    for (int p = 0; p < 4; ++p) {
        const int r = rr + p * 16;
        const size_t o = (size_t)(r0 + r) * 64 + c4;
        const float4 m = *reinterpret_cast<const float4*>(mu + o);
        const float4 l = *reinterpret_cast<const float4*>(lv + o);
        const float4 e = *reinterpret_cast<const float4*>(eps + o);
        t[r][c4 + 0] = m.x + expf(0.5f * l.x) * e.x;
        t[r][c4 + 1] = m.y + expf(0.5f * l.y) * e.y;
        t[r][c4 + 2] = m.z + expf(0.5f * l.z) * e.z;
        t[r][c4 + 3] = m.w + expf(0.5f * l.w) * e.w;
    }
    __syncthreads();
    const int lane = tid & 63, wid = tid >> 6;
    #pragma unroll
    for (int p = 0; p < 2; ++p) {
        const int g  = wid * 2 + p;
        const int ot = g >> 1, kb = g & 1;
        const int rI = ot * 16 + (lane & 15);
        const int kI = kb * 32 + (lane >> 4) * 8;
        f16x8 hv, lvv;
        #pragma unroll
        for (int j = 0; j < 8; ++j) {
            const float v = t[rI][kI + j];
            const _Float16 h = (_Float16)v;
            hv[j] = h; lvv[j] = (_Float16)(v - (float)h);
        }
        const size_t base = ((size_t)((r0 >> 4) + ot) * 2 + kb) * 1024;
        *reinterpret_cast<f16x8*>(zfm + base + lane * 8)       = hv;
        *reinterpret_cast<f16x8*>(zfm + base + 512 + lane * 8) = lvv;
    }
}

// ---------------------------------------------------------------------------
// Split-f16 GEMM v10: ZERO-LDS, ZERO-BARRIER main loop. Both operands loaded
// fragment-major direct global->VGPR (coalesced 16B/lane) with named
// ping-pong frag sets; compiler owns waitcnt/scheduling. LDS only for the
// MODE0 epilogue bounce.
// MODE 0/1: BM=128,BN=128, 4 waves 2x2, wave 64x64 (MF=4,NF=4), grid 512.
// MODE 2 (heads): BM=64, N=128 (mu|lv), 4 waves 2x2, wave 32x64, grid 256.
// XCD map: contiguous bx slab x all by per XCD -> A 4MB + W 1MB L2-fit.
// ---------------------------------------------------------------------------
template<int KA, int MODE>
__global__ __launch_bounds__(256, 2)
void gemm10(const _Float16* __restrict__ Afm, const _Float16* __restrict__ Wfm,
            const float* __restrict__ bias0, const float* __restrict__ bias1,
            float* __restrict__ Cf, float* __restrict__ Cf1,
            _Float16* __restrict__ Cfm, const float* __restrict__ Xin,
            float* __restrict__ rec8)
{
    constexpr bool BIG = (MODE != 2);
    constexpr int MF = BIG ? 4 : 2;
    constexpr int KB = KA / 32;
    constexpr int NT = KB;               // 16 or 2 (even)
    __shared__ __align__(16) uint8_t smem[(MODE == 0) ? 32768 : 64];

    const int bid = blockIdx.x;
    int bx, by;
    if (BIG) { bx = (bid & 7) * 16 + (bid >> 5); by = (bid >> 3) & 3; }
    else     { bx = (bid & 7) * 32 + (bid >> 3); by = 0; }

    const int lane = threadIdx.x & 63, wid = threadIdx.x >> 6;
    const int wr = wid >> 1, wc = wid & 1;
    const int row0 = bx * (BIG ? 128 : 64);
    const int col0 = by * 128;
    const int ct0  = (BIG ? (col0 >> 4) : 0) + wc * 4;

    const _Float16* aP[2 * MF];
    #pragma unroll
    for (int i = 0; i < 2 * MF; ++i)
        aP[i] = Afm + (size_t)((row0 >> 4) + wr * MF + (i >> 1)) * KB * 1024
                    + (i & 1) * 512 + lane * 8;
    const _Float16* wP[8];
    #pragma unroll
    for (int i = 0; i < 8; ++i)
        wP[i] = Wfm + (size_t)(ct0 + (i >> 1)) * KB * 1024
                    + (i & 1) * 512 + lane * 8;

    f32x4 acc[MF][4];
    #pragma unroll
    for (int i = 0; i < MF; ++i)
        #pragma unroll
        for (int j = 0; j < 4; ++j) acc[i][j] = {0.f, 0.f, 0.f, 0.f};

    f16x8 fa0[MF][2], fa1[MF][2], fw0[4][2], fw1[4][2];

#define LDA(dst)                                                             \
    { _Pragma("unroll")                                                      \
      for (int i = 0; i < 2 * MF; ++i) {                                     \
          dst[i >> 1][i & 1] = *reinterpret_cast<const f16x8*>(aP[i]);       \
          aP[i] += 1024;                                                     \
      } }
#define LDW(dst)                                                             \
    { _Pragma("unroll")                                                      \
      for (int i = 0; i < 8; ++i) {                                          \
          dst[i >> 1][i & 1] = *reinterpret_cast<const f16x8*>(wP[i]);       \
          wP[i] += 1024;                                                     \
      } }
#define MM(fa, fw)                                                           \
    { _Pragma("unroll")                                                      \
      for (int mf = 0; mf < MF; ++mf)                                        \
          _Pragma("unroll")                                                  \
          for (int nf = 0; nf < 4; ++nf) {                                   \
              acc[mf][nf] = __builtin_amdgcn_mfma_f32_16x16x32_f16(          \
                  fa[mf][0], fw[nf][0], acc[mf][nf], 0, 0, 0);               \
              acc[mf][nf] = __builtin_amdgcn_mfma_f32_16x16x32_f16(          \
                  fa[mf][0], fw[nf][1], acc[mf][nf], 0, 0, 0);               \
              acc[mf][nf] = __builtin_amdgcn_mfma_f32_16x16x32_f16(          \
                  fa[mf][1], fw[nf][0], acc[mf][nf], 0, 0, 0);               \
          } }

    LDA(fa0) LDW(fw0)
    if (NT > 1) { LDA(fa1) LDW(fw1) }

    for (int t = 0; t < NT; t += 2) {
        MM(fa0, fw0)
        if (t + 2 < NT) { LDA(fa0) LDW(fw0) }
        MM(fa1, fw1)
        if (t + 3 < NT) { LDA(fa1) LDW(fw1) }
    }
#undef MM
#undef LDW
#undef LDA

    // ---------------- epilogue ----------------
    if constexpr (MODE == 0) {
        uint32_t* sb = reinterpret_cast<uint32_t*>(smem);   // 128 x 64 u32
        #pragma unroll
        for (int ph = 0; ph < 2; ++ph) {
            if (wc == ph) {
                #pragma unroll
                for (int nf = 0; nf < 4; ++nf) {
                    const int c_l = nf * 16 + (lane & 15);       // 0..63
                    const float bv = bias0[col0 + ph * 64 + c_l];
                    #pragma unroll
                    for (int mf = 0; mf < 4; ++mf)
                        #pragma unroll
                        for (int j = 0; j < 4; ++j) {
                            const int r_l = wr * 64 + mf * 16 + (lane >> 4) * 4 + j;
                            const float v = fmaxf(acc[mf][nf][j] + bv, 0.f);
                            const _Float16 h = (_Float16)v;
                            const _Float16 lo = (_Float16)(v - (float)h);
                            const uint32_t pk =
                                (uint32_t)__builtin_bit_cast(uint16_t, h) |
                                ((uint32_t)__builtin_bit_cast(uint16_t, lo) << 16);
                            sb[r_l * 64 + (((c_l >> 2) ^ (r_l & 15)) << 2) + (c_l & 3)] = pk;
                        }
                }
            }
            __syncthreads();
            {   // copy-out: all 4 waves, 4 chunks each (8 T x 2 kb)
                #pragma unroll
                for (int i = 0; i < 4; ++i) {
                    const int q = wid * 4 + i;
                    const int T_l = q >> 1, kb_l = q & 1;
                    const int r_l = T_l * 16 + (lane & 15);
                    const int cb  = kb_l * 32 + (lane >> 4) * 8;
                    uint32_t u[8];
                    #pragma unroll
                    for (int jb = 0; jb < 2; ++jb) {
                        const int chunk = ((cb >> 2) + jb) ^ (r_l & 15);
                        const uint32_t* pp = &sb[r_l * 64 + chunk * 4];
                        u[jb*4+0] = pp[0]; u[jb*4+1] = pp[1];
                        u[jb*4+2] = pp[2]; u[jb*4+3] = pp[3];
                    }
                    f16x8 hv, lvv;
                    #pragma unroll
                    for (int j = 0; j < 8; ++j) {
                        hv[j]  = __builtin_bit_cast(_Float16, (uint16_t)(u[j] & 0xffff));
                        lvv[j] = __builtin_bit_cast(_Float16, (uint16_t)(u[j] >> 16));
                    }
                    const size_t base =
                        ((size_t)((row0 >> 4) + T_l) * 16 +
                         ((col0 + ph * 64) >> 5) + kb_l) * 1024;
                    *reinterpret_cast<f16x8*>(Cfm + base + lane * 8)       = hv;
                    *reinterpret_cast<f16x8*>(Cfm + base + 512 + lane * 8) = lvv;
                }
            }
            __syncthreads();
        }
    } else if constexpr (MODE == 1) {
        float rsum[4][4];
        #pragma unroll
        for (int mf = 0; mf < 4; ++mf)
            #pragma unroll
            for (int j = 0; j < 4; ++j) rsum[mf][j] = 0.f;
        #pragma unroll
        for (int nf = 0; nf < 4; ++nf) {
            const int col = col0 + wc * 64 + nf * 16 + (lane & 15);
            const float bv = bias0[col];
            #pragma unroll
            for (int mf = 0; mf < 4; ++mf)
                #pragma unroll
                for (int j = 0; j < 4; ++j) {
                    const int row = row0 + wr * 64 + mf * 16 + (lane >> 4) * 4 + j;
                    const float v = acc[mf][nf][j] + bv;
                    Cf[(size_t)row * 512 + col] = v;
                    const float d = v - Xin[(size_t)row * 512 + col];
                    rsum[mf][j] += d * d;
                }
        }
        #pragma unroll
        for (int mf = 0; mf < 4; ++mf)
            #pragma unroll
            for (int j = 0; j < 4; ++j) {
                float s = rsum[mf][j];
                s += __shfl_xor(s, 1); s += __shfl_xor(s, 2);
                s += __shfl_xor(s, 4); s += __shfl_xor(s, 8);
                if ((lane & 15) == 0) {
                    const int row = row0 + wr * 64 + mf * 16 + (lane >> 4) * 4 + j;
                    rec8[(size_t)(by * 2 + wc) * Bb + row] = s;
                }
            }
    } else {   // MODE 2: heads, wave cols wc*64.. ; col<64 -> mu, else lv
        #pragma unroll
        for (int nf = 0; nf < 4; ++nf) {
            const int c_h = wc * 64 + nf * 16 + (lane & 15);   // 0..127
            const float bv = (c_h < 64) ? bias0[c_h] : bias1[c_h - 64];
            float* CP = (c_h < 64) ? Cf : Cf1;
            const int c = c_h & 63;
            #pragma unroll
            for (int mf = 0; mf < MF; ++mf)
                #pragma unroll
                for (int j = 0; j < 4; ++j) {
                    const int row = row0 + wr * 32 + mf * 16 + (lane >> 4) * 4 + j;
                    CP[(size_t)row * 64 + c] = acc[mf][nf][j] + bv;
                }
        }
    }
}

// sum 8 partials, running-min select + gather
__global__ __launch_bounds__(256)
void select_kernel(const float* __restrict__ rec8, float* __restrict__ best,
                   const float* __restrict__ mu_e, const float* __restrict__ lv_e,
                   const float* __restrict__ xhat,
                   float* __restrict__ out_mu, float* __restrict__ out_lv,
                   float* __restrict__ out_xh, int isFirst)
{
    const int wave = threadIdx.x >> 6;
    const int lane = threadIdx.x & 63;
    const int row  = blockIdx.x * 4 + wave;
    float r = 0.f;
    #pragma unroll
    for (int p = 0; p < 8; ++p) r += rec8[(size_t)p * Bb + row];
    r *= (1.0f / 512.0f);
    const bool cond = isFirst || (r < best[row]);
    if (cond) {
        if (lane == 0) best[row] = r;
        out_mu[(size_t)row * Zz + lane] = mu_e[(size_t)row * Zz + lane];
        out_lv[(size_t)row * Zz + lane] = lv_e[(size_t)row * Zz + lane];
        const float4* src = reinterpret_cast<const float4*>(&xhat[(size_t)row * Dd]);
        float4*       dst = reinterpret_cast<float4*>(&out_xh[(size_t)row * Dd]);
        dst[lane]      = src[lane];
        dst[lane + 64] = src[lane + 64];
    }
}

extern "C" void kernel_launch(void* const* d_in, const int* in_sizes, int n_in,
                              void* d_out, int out_size, void* d_ws, size_t ws_size,
                              hipStream_t stream)
{
    const float* x         = (const float*)d_in[0];
    const float* eps       = (const float*)d_in[1];
    const float* enc_in_w  = (const float*)d_in[2];
    const float* enc_in_b  = (const float*)d_in[3];
    const float* enc_hid_w = (const float*)d_in[4];
    const float* enc_hid_b = (const float*)d_in[5];
    const float* mu_w      = (const float*)d_in[6];
    const float* mu_b      = (const float*)d_in[7];
    const float* lv_w      = (const float*)d_in[8];
    const float* lv_b      = (const float*)d_in[9];
    const float* dec_in_w  = (const float*)d_in[10];
    const float* dec_in_b  = (const float*)d_in[11];
    const float* dec_hid_w = (const float*)d_in[12];
    const float* dec_hid_b = (const float*)d_in[13];
    const float* dec_out_w = (const float*)d_in[14];
    const float* dec_out_b = (const float*)d_in[15];

    const size_t FM = (size_t)Bb * 512 * 2;
    const size_t BZ = (size_t)Bb * 64;

    _Float16* wt  = (_Float16*)d_ws;
    _Float16* xfm = wt + WT_TOTAL;
    _Float16* afm = xfm + FM;
    _Float16* bfm = afm + FM;
    _Float16* zfm = bfm + FM;
    float* fbase  = (float*)(zfm + (size_t)Bb * 64 * 2);
    float* xhat   = fbase;
    float* mu_e   = xhat + (size_t)Bb * 512;
    float* lv_e   = mu_e + BZ;
    float* rec8   = lv_e + BZ;
    float* best   = rec8 + (size_t)8 * Bb;

    float* out_mu = (float*)d_out;
    float* out_lv = out_mu + (size_t)Bb * Zz;
    float* out_xh = out_lv + (size_t)Bb * Zz;

    const dim3 blk(256);

    fmsplit<true ><<<dim3(8, 8, 8), blk, 0, stream>>>(enc_in_w,           wt + OFF_ENCIN,  512, 512, 262144, PEREXP);
    fmsplit<true ><<<dim3(8, 8, 8), blk, 0, stream>>>(enc_hid_w,          wt + OFF_HID0,   512, 512, 524288, PEREXP);
    fmsplit<true ><<<dim3(8, 8, 8), blk, 0, stream>>>(enc_hid_w + 262144, wt + OFF_HID1,   512, 512, 524288, PEREXP);
    fmsplit<true ><<<dim3(1, 8, 8), blk, 0, stream>>>(mu_w,               wt + OFF_HEADS,  512,  64,  32768, PEREXP);
    fmsplit<true ><<<dim3(1, 8, 8), blk, 0, stream>>>(lv_w,        wt + OFF_HEADS + 65536, 512,  64,  32768, PEREXP);
    fmsplit<true ><<<dim3(8, 1, 8), blk, 0, stream>>>(dec_in_w,           wt + OFF_DECIN,   64, 512,  32768, PEREXP);
    fmsplit<true ><<<dim3(8, 8, 8), blk, 0, stream>>>(dec_hid_w,          wt + OFF_DHID0,  512, 512, 524288, PEREXP);
    fmsplit<true ><<<dim3(8, 8, 8), blk, 0, stream>>>(dec_hid_w + 262144, wt + OFF_DHID1,  512, 512, 524288, PEREXP);
    fmsplit<true ><<<dim3(8, 8, 8), blk, 0, stream>>>(dec_out_w,          wt + OFF_DECOUT, 512, 512, 262144, PEREXP);
    fmsplit<false><<<dim3(256, 8, 1), blk, 0, stream>>>(x,                xfm,             512, 512, 0, 0);

    const dim3 g512(512), g256(256), gRow(Bb / 4), gZ(Bb / 64);

    for (int e = 0; e < Eexp; ++e) {
        const _Float16* we = wt + (size_t)e * PEREXP;
        gemm10<512, 0><<<g512, blk, 0, stream>>>(
            xfm, we + OFF_ENCIN, enc_in_b + (size_t)e * Hh, nullptr,
            nullptr, nullptr, afm, nullptr, nullptr);
        gemm10<512, 0><<<g512, blk, 0, stream>>>(
            afm, we + OFF_HID0, enc_hid_b + ((size_t)e * 2 + 0) * Hh, nullptr,
            nullptr, nullptr, bfm, nullptr, nullptr);
        gemm10<512, 0><<<g512, blk, 0, stream>>>(
            bfm, we + OFF_HID1, enc_hid_b + ((size_t)e * 2 + 1) * Hh, nullptr,
            nullptr, nullptr, afm, nullptr, nullptr);
        gemm10<512, 2><<<g256, blk, 0, stream>>>(
            afm, we + OFF_HEADS, mu_b + (size_t)e * Zz, lv_b + (size_t)e * Zz,
            mu_e, lv_e, nullptr, nullptr, nullptr);
        zfm_kernel<<<gZ, blk, 0, stream>>>(mu_e, lv_e, eps, zfm);
        gemm10< 64, 0><<<g512, blk, 0, stream>>>(
            zfm, we + OFF_DECIN, dec_in_b + (size_t)e * Hh, nullptr,
            nullptr, nullptr, bfm, nullptr, nullptr);
        gemm10<512, 0><<<g512, blk, 0, stream>>>(
            bfm, we + OFF_DHID0, dec_hid_b + ((size_t)e * 2 + 0) * Hh, nullptr,
            nullptr, nullptr, afm, nullptr, nullptr);
        gemm10<512, 0><<<g512, blk, 0, stream>>>(
            afm, we + OFF_DHID1, dec_hid_b + ((size_t)e * 2 + 1) * Hh, nullptr,
            nullptr, nullptr, bfm, nullptr, nullptr);
        gemm10<512, 1><<<g512, blk, 0, stream>>>(
            bfm, we + OFF_DECOUT, dec_out_b + (size_t)e * Dd, nullptr,
            xhat, nullptr, nullptr, x, rec8);
        select_kernel<<<gRow, blk, 0, stream>>>(
            rec8, best, mu_e, lv_e, xhat, out_mu, out_lv, out_xh, e == 0 ? 1 : 0);
    }
}

// Round 11
// 1737.050 us; speedup vs baseline: 1.5486x; 1.5486x over previous
//
#include <hip/hip_runtime.h>
#include <cstdint>

#define Eexp 8
#define Bb   16384
#define Dd   512
#define Hh   512
#define Zz   64

typedef _Float16 f16x8 __attribute__((ext_vector_type(8)));
typedef float    f32x4 __attribute__((ext_vector_type(4)));

// fm16 layout: per (T=row/16, kb=k/32) a 1024-f16 block [hi 512 | lo 512];
// lane l elem j = M[T*16 + (l&15)][kb*32 + (l>>4)*8 + j]
#define OFF_ENCIN  0
#define OFF_HID0   524288
#define OFF_HID1   1048576
#define OFF_HEADS  1572864   /* mu tiles T0..3, lv tiles T4..7 */
#define OFF_DECIN  1703936
#define OFF_DHID0  1769472
#define OFF_DHID1  2293760
#define OFF_DECOUT 2818048
#define PEREXP     3342336
#define WT_TOTAL   (8 * (size_t)PEREXP)

#define GLL16(g, l) __builtin_amdgcn_global_load_lds( \
    (const __attribute__((address_space(1))) void*)(g), \
    (__attribute__((address_space(3))) void*)(l), 16, 0, 0)

// ---------------------------------------------------------------------------
// fp32 src -> fm16 split-f16. TR: src[K,N] (weights). !TR: src[M,K] (x).
// ---------------------------------------------------------------------------
template<bool TR>
__global__ __launch_bounds__(256)
void fmsplit(const float* __restrict__ src, _Float16* __restrict__ dst,
             int KTOT, int inner, long sStride, long dStride)
{
    __shared__ float t[64][65];
    const int e  = blockIdx.z;
    const int o0 = blockIdx.x * 64;
    const int k0 = blockIdx.y * 64;
    const float* S = src + (size_t)e * sStride;
    _Float16*    D = dst + (size_t)e * dStride;
    const int tid = threadIdx.x;
    const int rr = tid >> 4, c4 = (tid & 15) * 4;
    #pragma unroll
    for (int p = 0; p < 4; ++p) {
        const int r = rr + p * 16;
        const float4 v = *reinterpret_cast<const float4*>(
            S + (size_t)(TR ? (k0 + r) : (o0 + r)) * inner + (TR ? o0 : k0) + c4);
        t[r][c4 + 0] = v.x; t[r][c4 + 1] = v.y;
        t[r][c4 + 2] = v.z; t[r][c4 + 3] = v.w;
    }
    __syncthreads();
    const int lane = tid & 63, wid = tid >> 6;
    const int KB = KTOT >> 5;
    #pragma unroll
    for (int p = 0; p < 2; ++p) {
        const int g  = wid * 2 + p;          // 0..7 = (ot 0..3, kb 0..1)
        const int ot = g >> 1, kb = g & 1;
        const int rI = ot * 16 + (lane & 15);
        const int kI = kb * 32 + (lane >> 4) * 8;
        f16x8 hv, lv;
        #pragma unroll
        for (int j = 0; j < 8; ++j) {
            const float v = TR ? t[kI + j][rI] : t[rI][kI + j];
            const _Float16 h = (_Float16)v;
            hv[j] = h; lv[j] = (_Float16)(v - (float)h);
        }
        const size_t base = ((size_t)((o0 >> 4) + ot) * KB + (k0 >> 5) + kb) * 1024;
        *reinterpret_cast<f16x8*>(D + base + lane * 8)       = hv;
        *reinterpret_cast<f16x8*>(D + base + 512 + lane * 8) = lv;
    }
}

// z = mu + exp(0.5*lv)*eps -> fm16 split. grid B/64, K=64 (KB=2).
__global__ __launch_bounds__(256)
void zfm_kernel(const float* __restrict__ mu, const float* __restrict__ lv,
                const float* __restrict__ eps, _Float16* __restrict__ zfm)
{
    __shared__ float t[64][65];
    const int r0 = blockIdx.x * 64;
    const int tid = threadIdx.x, rr = tid >> 4, c4 = (tid & 15) * 4;
    #pragma unroll
    for (int p = 0; p < 4; ++p) {
        const int r = rr + p * 16;
        const size_t o = (size_t)(r0 + r) * 64 + c4;
        const float4 m = *reinterpret_cast<const float4*>(mu + o);
        const float4 l = *reinterpret_cast<const float4*>(lv + o);
        const float4 e = *reinterpret_cast<const float4*>(eps + o);
        t[r][c4 + 0] = m.x + expf(0.5f * l.x) * e.x;
        t[r][c4 + 1] = m.y + expf(0.5f * l.y) * e.y;
        t[r][c4 + 2] = m.z + expf(0.5f * l.z) * e.z;
        t[r][c4 + 3] = m.w + expf(0.5f * l.w) * e.w;
    }
    __syncthreads();
    const int lane = tid & 63, wid = tid >> 6;
    #pragma unroll
    for (int p = 0; p < 2; ++p) {
        const int g  = wid * 2 + p;
        const int ot = g >> 1, kb = g & 1;
        const int rI = ot * 16 + (lane & 15);
        const int kI = kb * 32 + (lane >> 4) * 8;
        f16x8 hv, lvv;
        #pragma unroll
        for (int j = 0; j < 8; ++j) {
            const float v = t[rI][kI + j];
            const _Float16 h = (_Float16)v;
            hv[j] = h; lvv[j] = (_Float16)(v - (float)h);
        }
        const size_t base = ((size_t)((r0 >> 4) + ot) * 2 + kb) * 1024;
        *reinterpret_cast<f16x8*>(zfm + base + lane * 8)       = hv;
        *reinterpret_cast<f16x8*>(zfm + base + 512 + lane * 8) = lvv;
    }
}

// ---------------------------------------------------------------------------
// Split-f16 GEMM v11: BOTH operands staged once per block via global_load_lds
// (TA traffic deduped), fragments read from LDS. Ring-2, r9's proven counted
// vmcnt schedule: wait vmcnt(GPW) at top, STAGE(t+2) after post-MFMA barrier.
// MODE 0/1: BM=128,BN=128, 4 waves 2x2, wave 64x64 (MF=4,NF=4), grid 512.
// MODE 2 (heads): BM=64, N=128 (mu|lv), 4 waves 2x2, wave 32x64, grid 256.
// XCD map: contiguous bx slab x all by per XCD -> A 4MB + W 1MB L2-fit.
// ---------------------------------------------------------------------------
template<int KA, int MODE>
__global__ __launch_bounds__(256, 2)
void gemm11(const _Float16* __restrict__ Afm, const _Float16* __restrict__ Wfm,
            const float* __restrict__ bias0, const float* __restrict__ bias1,
            float* __restrict__ Cf, float* __restrict__ Cf1,
            _Float16* __restrict__ Cfm, const float* __restrict__ Xin,
            float* __restrict__ rec8)
{
    constexpr bool BIG = (MODE != 2);
    constexpr int MF  = BIG ? 4 : 2;
    constexpr int KB  = KA / 32;
    constexpr int NT  = KB;                 // 16 or 2
    constexpr int ACH = BIG ? 16 : 8;       // A chunks (512 f16) per k-step
    constexpr int NCH = ACH + 16;           // + W chunks (N=128 always)
    constexpr int GPW = NCH / 4;            // GLL per wave per k-step (8 / 6)
    __shared__ __align__(16) _Float16 lds[2 * NCH * 512];

    const int bid = blockIdx.x;
    int bx, by;
    if (BIG) { bx = (bid & 7) * 16 + (bid >> 5); by = (bid >> 3) & 3; }
    else     { bx = (bid & 7) * 32 + (bid >> 3); by = 0; }

    const int lane = threadIdx.x & 63, wid = threadIdx.x >> 6;
    const int wr = wid >> 1, wc = wid & 1;
    const int row0 = bx * (BIG ? 128 : 64);
    const int col0 = by * 128;

    // staging source pointers (advance +1024 elems per k-step)
    const _Float16* src[GPW];
    #pragma unroll
    for (int p = 0; p < GPW; ++p) {
        const int q = wid * GPW + p;
        if (q < ACH)
            src[p] = Afm + (size_t)((row0 >> 4) + (q >> 1)) * KB * 1024
                         + (q & 1) * 512 + lane * 8;
        else {
            const int qq = q - ACH;
            src[p] = Wfm + (size_t)((col0 >> 4) + (qq >> 1)) * KB * 1024
                         + (qq & 1) * 512 + lane * 8;
        }
    }

    f32x4 acc[MF][4];
    #pragma unroll
    for (int i = 0; i < MF; ++i)
        #pragma unroll
        for (int j = 0; j < 4; ++j) acc[i][j] = {0.f, 0.f, 0.f, 0.f};

#define STAGE(buf)                                                           \
    { _Pragma("unroll")                                                      \
      for (int p = 0; p < GPW; ++p) {                                        \
          GLL16(src[p], lds + (buf) * (NCH * 512) + (wid * GPW + p) * 512);  \
          src[p] += 1024;                                                    \
      } }

    STAGE(0)
    if (NT > 1) STAGE(1)

    for (int t = 0; t < NT; ++t) {
        if (t + 1 < NT) { asm volatile("s_waitcnt vmcnt(%0)" :: "i"(GPW) : "memory"); }
        else            { asm volatile("s_waitcnt vmcnt(0)" ::: "memory"); }
        __builtin_amdgcn_s_barrier();
        asm volatile("" ::: "memory");

        const _Float16* B0 = lds + (t & 1) * (NCH * 512);
        f16x8 ah[MF], al[MF], wh[4], wl[4];
        #pragma unroll
        for (int mf = 0; mf < MF; ++mf) {
            const int q = (wr * MF + mf) * 2;
            ah[mf] = *reinterpret_cast<const f16x8*>(B0 + q * 512 + lane * 8);
            al[mf] = *reinterpret_cast<const f16x8*>(B0 + q * 512 + 512 + lane * 8);
        }
        #pragma unroll
        for (int nf = 0; nf < 4; ++nf) {
            const int q = ACH + (wc * 4 + nf) * 2;
            wh[nf] = *reinterpret_cast<const f16x8*>(B0 + q * 512 + lane * 8);
            wl[nf] = *reinterpret_cast<const f16x8*>(B0 + q * 512 + 512 + lane * 8);
        }
        __builtin_amdgcn_s_setprio(1);
        #pragma unroll
        for (int mf = 0; mf < MF; ++mf)
            #pragma unroll
            for (int nf = 0; nf < 4; ++nf) {
                acc[mf][nf] = __builtin_amdgcn_mfma_f32_16x16x32_f16(
                    ah[mf], wh[nf], acc[mf][nf], 0, 0, 0);
                acc[mf][nf] = __builtin_amdgcn_mfma_f32_16x16x32_f16(
                    ah[mf], wl[nf], acc[mf][nf], 0, 0, 0);
                acc[mf][nf] = __builtin_amdgcn_mfma_f32_16x16x32_f16(
                    al[mf], wh[nf], acc[mf][nf], 0, 0, 0);
            }
        __builtin_amdgcn_s_setprio(0);
        asm volatile("" ::: "memory");
        __builtin_amdgcn_s_barrier();
        asm volatile("" ::: "memory");
        if (t + 2 < NT) STAGE(t & 1)
    }
#undef STAGE

    // ---------------- epilogue ----------------
    if constexpr (MODE == 0) {
        uint32_t* sb = reinterpret_cast<uint32_t*>(&lds[0]);   // 128 x 64 u32
        #pragma unroll
        for (int ph = 0; ph < 2; ++ph) {
            if (wc == ph) {
                #pragma unroll
                for (int nf = 0; nf < 4; ++nf) {
                    const int c_l = nf * 16 + (lane & 15);       // 0..63
                    const float bv = bias0[col0 + ph * 64 + c_l];
                    #pragma unroll
                    for (int mf = 0; mf < 4; ++mf)
                        #pragma unroll
                        for (int j = 0; j < 4; ++j) {
                            const int r_l = wr * 64 + mf * 16 + (lane >> 4) * 4 + j;
                            const float v = fmaxf(acc[mf][nf][j] + bv, 0.f);
                            const _Float16 h = (_Float16)v;
                            const _Float16 lo = (_Float16)(v - (float)h);
                            const uint32_t pk =
                                (uint32_t)__builtin_bit_cast(uint16_t, h) |
                                ((uint32_t)__builtin_bit_cast(uint16_t, lo) << 16);
                            sb[r_l * 64 + (((c_l >> 2) ^ (r_l & 15)) << 2) + (c_l & 3)] = pk;
                        }
                }
            }
            __syncthreads();
            {   // copy-out: all 4 waves, 4 chunks each (8 T x 2 kb)
                #pragma unroll
                for (int i = 0; i < 4; ++i) {
                    const int q = wid * 4 + i;
                    const int T_l = q >> 1, kb_l = q & 1;
                    const int r_l = T_l * 16 + (lane & 15);
                    const int cb  = kb_l * 32 + (lane >> 4) * 8;
                    uint32_t u[8];
                    #pragma unroll
                    for (int jb = 0; jb < 2; ++jb) {
                        const int chunk = ((cb >> 2) + jb) ^ (r_l & 15);
                        const uint32_t* pp = &sb[r_l * 64 + chunk * 4];
                        u[jb*4+0] = pp[0]; u[jb*4+1] = pp[1];
                        u[jb*4+2] = pp[2]; u[jb*4+3] = pp[3];
                    }
                    f16x8 hv, lvv;
                    #pragma unroll
                    for (int j = 0; j < 8; ++j) {
                        hv[j]  = __builtin_bit_cast(_Float16, (uint16_t)(u[j] & 0xffff));
                        lvv[j] = __builtin_bit_cast(_Float16, (uint16_t)(u[j] >> 16));
                    }
                    const size_t base =
                        ((size_t)((row0 >> 4) + T_l) * 16 +
                         ((col0 + ph * 64) >> 5) + kb_l) * 1024;
                    *reinterpret_cast<f16x8*>(Cfm + base + lane * 8)       = hv;
                    *reinterpret_cast<f16x8*>(Cfm + base + 512 + lane * 8) = lvv;
                }
            }
            __syncthreads();
        }
    } else if constexpr (MODE == 1) {
        float rsum[4][4];
        #pragma unroll
        for (int mf = 0; mf < 4; ++mf)
            #pragma unroll
            for (int j = 0; j < 4; ++j) rsum[mf][j] = 0.f;
        #pragma unroll
        for (int nf = 0; nf < 4; ++nf) {
            const int col = col0 + wc * 64 + nf * 16 + (lane & 15);
            const float bv = bias0[col];
            #pragma unroll
            for (int mf = 0; mf < 4; ++mf)
                #pragma unroll
                for (int j = 0; j < 4; ++j) {
                    const int row = row0 + wr * 64 + mf * 16 + (lane >> 4) * 4 + j;
                    const float v = acc[mf][nf][j] + bv;
                    Cf[(size_t)row * 512 + col] = v;
                    const float d = v - Xin[(size_t)row * 512 + col];
                    rsum[mf][j] += d * d;
                }
        }
        #pragma unroll
        for (int mf = 0; mf < 4; ++mf)
            #pragma unroll
            for (int j = 0; j < 4; ++j) {
                float s = rsum[mf][j];
                s += __shfl_xor(s, 1); s += __shfl_xor(s, 2);
                s += __shfl_xor(s, 4); s += __shfl_xor(s, 8);
                if ((lane & 15) == 0) {
                    const int row = row0 + wr * 64 + mf * 16 + (lane >> 4) * 4 + j;
                    rec8[(size_t)(by * 2 + wc) * Bb + row] = s;
                }
            }
    } else {   // MODE 2: heads, wave cols wc*64.. ; col<64 -> mu, else lv
        #pragma unroll
        for (int nf = 0; nf < 4; ++nf) {
            const int c_h = wc * 64 + nf * 16 + (lane & 15);   // 0..127
            const float bv = (c_h < 64) ? bias0[c_h] : bias1[c_h - 64];
            float* CP = (c_h < 64) ? Cf : Cf1;
            const int c = c_h & 63;
            #pragma unroll
            for (int mf = 0; mf < MF; ++mf)
                #pragma unroll
                for (int j = 0; j < 4; ++j) {
                    const int row = row0 + wr * 32 + mf * 16 + (lane >> 4) * 4 + j;
                    CP[(size_t)row * 64 + c] = acc[mf][nf][j] + bv;
                }
        }
    }
}

// sum 8 partials, running-min select + gather
__global__ __launch_bounds__(256)
void select_kernel(const float* __restrict__ rec8, float* __restrict__ best,
                   const float* __restrict__ mu_e, const float* __restrict__ lv_e,
                   const float* __restrict__ xhat,
                   float* __restrict__ out_mu, float* __restrict__ out_lv,
                   float* __restrict__ out_xh, int isFirst)
{
    const int wave = threadIdx.x >> 6;
    const int lane = threadIdx.x & 63;
    const int row  = blockIdx.x * 4 + wave;
    float r = 0.f;
    #pragma unroll
    for (int p = 0; p < 8; ++p) r += rec8[(size_t)p * Bb + row];
    r *= (1.0f / 512.0f);
    const bool cond = isFirst || (r < best[row]);
    if (cond) {
        if (lane == 0) best[row] = r;
        out_mu[(size_t)row * Zz + lane] = mu_e[(size_t)row * Zz + lane];
        out_lv[(size_t)row * Zz + lane] = lv_e[(size_t)row * Zz + lane];
        const float4* src = reinterpret_cast<const float4*>(&xhat[(size_t)row * Dd]);
        float4*       dst = reinterpret_cast<float4*>(&out_xh[(size_t)row * Dd]);
        dst[lane]      = src[lane];
        dst[lane + 64] = src[lane + 64];
    }
}

extern "C" void kernel_launch(void* const* d_in, const int* in_sizes, int n_in,
                              void* d_out, int out_size, void* d_ws, size_t ws_size,
                              hipStream_t stream)
{
    const float* x         = (const float*)d_in[0];
    const float* eps       = (const float*)d_in[1];
    const float* enc_in_w  = (const float*)d_in[2];
    const float* enc_in_b  = (const float*)d_in[3];
    const float* enc_hid_w = (const float*)d_in[4];
    const float* enc_hid_b = (const float*)d_in[5];
    const float* mu_w      = (const float*)d_in[6];
    const float* mu_b      = (const float*)d_in[7];
    const float* lv_w      = (const float*)d_in[8];
    const float* lv_b      = (const float*)d_in[9];
    const float* dec_in_w  = (const float*)d_in[10];
    const float* dec_in_b  = (const float*)d_in[11];
    const float* dec_hid_w = (const float*)d_in[12];
    const float* dec_hid_b = (const float*)d_in[13];
    const float* dec_out_w = (const float*)d_in[14];
    const float* dec_out_b = (const float*)d_in[15];

    const size_t FM = (size_t)Bb * 512 * 2;
    const size_t BZ = (size_t)Bb * 64;

    _Float16* wt  = (_Float16*)d_ws;
    _Float16* xfm = wt + WT_TOTAL;
    _Float16* afm = xfm + FM;
    _Float16* bfm = afm + FM;
    _Float16* zfm = bfm + FM;
    float* fbase  = (float*)(zfm + (size_t)Bb * 64 * 2);
    float* xhat   = fbase;
    float* mu_e   = xhat + (size_t)Bb * 512;
    float* lv_e   = mu_e + BZ;
    float* rec8   = lv_e + BZ;
    float* best   = rec8 + (size_t)8 * Bb;

    float* out_mu = (float*)d_out;
    float* out_lv = out_mu + (size_t)Bb * Zz;
    float* out_xh = out_lv + (size_t)Bb * Zz;

    const dim3 blk(256);

    fmsplit<true ><<<dim3(8, 8, 8), blk, 0, stream>>>(enc_in_w,           wt + OFF_ENCIN,  512, 512, 262144, PEREXP);
    fmsplit<true ><<<dim3(8, 8, 8), blk, 0, stream>>>(enc_hid_w,          wt + OFF_HID0,   512, 512, 524288, PEREXP);
    fmsplit<true ><<<dim3(8, 8, 8), blk, 0, stream>>>(enc_hid_w + 262144, wt + OFF_HID1,   512, 512, 524288, PEREXP);
    fmsplit<true ><<<dim3(1, 8, 8), blk, 0, stream>>>(mu_w,               wt + OFF_HEADS,  512,  64,  32768, PEREXP);
    fmsplit<true ><<<dim3(1, 8, 8), blk, 0, stream>>>(lv_w,        wt + OFF_HEADS + 65536, 512,  64,  32768, PEREXP);
    fmsplit<true ><<<dim3(8, 1, 8), blk, 0, stream>>>(dec_in_w,           wt + OFF_DECIN,   64, 512,  32768, PEREXP);
    fmsplit<true ><<<dim3(8, 8, 8), blk, 0, stream>>>(dec_hid_w,          wt + OFF_DHID0,  512, 512, 524288, PEREXP);
    fmsplit<true ><<<dim3(8, 8, 8), blk, 0, stream>>>(dec_hid_w + 262144, wt + OFF_DHID1,  512, 512, 524288, PEREXP);
    fmsplit<true ><<<dim3(8, 8, 8), blk, 0, stream>>>(dec_out_w,          wt + OFF_DECOUT, 512, 512, 262144, PEREXP);
    fmsplit<false><<<dim3(256, 8, 1), blk, 0, stream>>>(x,                xfm,             512, 512, 0, 0);

    const dim3 g512(512), g256(256), gRow(Bb / 4), gZ(Bb / 64);

    for (int e = 0; e < Eexp; ++e) {
        const _Float16* we = wt + (size_t)e * PEREXP;
        gemm11<512, 0><<<g512, blk, 0, stream>>>(
            xfm, we + OFF_ENCIN, enc_in_b + (size_t)e * Hh, nullptr,
            nullptr, nullptr, afm, nullptr, nullptr);
        gemm11<512, 0><<<g512, blk, 0, stream>>>(
            afm, we + OFF_HID0, enc_hid_b + ((size_t)e * 2 + 0) * Hh, nullptr,
            nullptr, nullptr, bfm, nullptr, nullptr);
        gemm11<512, 0><<<g512, blk, 0, stream>>>(
            bfm, we + OFF_HID1, enc_hid_b + ((size_t)e * 2 + 1) * Hh, nullptr,
            nullptr, nullptr, afm, nullptr, nullptr);
        gemm11<512, 2><<<g256, blk, 0, stream>>>(
            afm, we + OFF_HEADS, mu_b + (size_t)e * Zz, lv_b + (size_t)e * Zz,
            mu_e, lv_e, nullptr, nullptr, nullptr);
        zfm_kernel<<<gZ, blk, 0, stream>>>(mu_e, lv_e, eps, zfm);
        gemm11< 64, 0><<<g512, blk, 0, stream>>>(
            zfm, we + OFF_DECIN, dec_in_b + (size_t)e * Hh, nullptr,
            nullptr, nullptr, bfm, nullptr, nullptr);
        gemm11<512, 0><<<g512, blk, 0, stream>>>(
            bfm, we + OFF_DHID0, dec_hid_b + ((size_t)e * 2 + 0) * Hh, nullptr,
            nullptr, nullptr, afm, nullptr, nullptr);
        gemm11<512, 0><<<g512, blk, 0, stream>>>(
            afm, we + OFF_DHID1, dec_hid_b + ((size_t)e * 2 + 1) * Hh, nullptr,
            nullptr, nullptr, bfm, nullptr, nullptr);
        gemm11<512, 1><<<g512, blk, 0, stream>>>(
            bfm, we + OFF_DECOUT, dec_out_b + (size_t)e * Dd, nullptr,
            xhat, nullptr, nullptr, x, rec8);
        select_kernel<<<gRow, blk, 0, stream>>>(
            rec8, best, mu_e, lv_e, xhat, out_mu, out_lv, out_xh, e == 0 ? 1 : 0);
    }
}